// Round 1
// baseline (236.588 us; speedup 1.0000x reference)
//
#include <hip/hip_runtime.h>
#include <math.h>

#define B_    64
#define N_    512
#define SEM_  256
#define STR_  256
#define DIM_  512              // SEM+STR
#define ROWS_ (B_*N_)          // 32768

// ---- workspace layout (float offsets) ----
#define OFF_Q      0           // 256x256
#define OFF_T      65536       // 256x256  (Wbil@Wp temp)
#define OFF_WT1    131072      // 256x256  Wt1[d][o] = Wfz[o][d]
#define OFF_V1     196608      // 256      Wfz2 @ exparam
#define OFF_C1     196864      // 256      Wp^T (Wbil+Wbil^T) bp
#define OFF_H      197120      // 256
#define OFF_C0     197376      // 1 (padded to 64)
#define OFF_EV     197440      // 32768  e_i = exp(s_i)
#define OFF_FV     230208      // 32768  f_i
#define OFF_SUMP   262976      // 64*4*256 partial sum_{j>=1} e_j sem[b,j,:]
#define OFF_FPART  328512      // 256
#define OFF_FWS    328768      // 64     F per batch
#define OFF_V2B    328832      // 64*256 e0 * Wfz2 @ sem[b,0,:]
#define OFF_V0B    345216      // 64*256 Wfz2 @ sumvec_b

// ============ K0a: T = Wbil@Wp, Wt1 transpose, v1, h, c0 ============
__global__ __launch_bounds__(256) void k0a(
    const float* __restrict__ Wp, const float* __restrict__ bp,
    const float* __restrict__ Wbil, const float* __restrict__ Wfz,
    const float* __restrict__ exparam,
    float* __restrict__ T, float* __restrict__ Wt1, float* __restrict__ v1,
    float* __restrict__ h, float* __restrict__ c0)
{
    int t = threadIdx.x;
    int bk = blockIdx.x;
    // T[a,e] = sum_c Wbil[a,c] * Wp[c,e]   (4 rows per block, e = t)
    for (int m = 0; m < 4; ++m) {
        int a = bk*4 + m;
        float acc = 0.f;
        const float* wb = Wbil + a*256;
        for (int c = 0; c < 256; ++c) acc += wb[c] * Wp[c*256 + t];
        T[a*256 + t] = acc;
    }
    // Wt1[d][o] = Wfz[o][d]  (first 256 cols of Wfz)
    for (int m = 0; m < 4; ++m) {
        int d = bk*4 + m;
        Wt1[d*256 + t] = Wfz[t*512 + d];
    }
    if (bk == 0) {
        // v1[o] = sum_d Wfz[o][256+d] * exparam[d]
        float acc = 0.f;
        const float* w2 = Wfz + t*512 + 256;
        for (int dd = 0; dd < 256; ++dd) acc += w2[dd] * exparam[dd];
        v1[t] = acc;
    }
    if (bk == 1) {
        // h = (Wbil + Wbil^T) bp ; c0 = bp^T Wbil bp
        float g = 0.f, g2 = 0.f;
        for (int c = 0; c < 256; ++c) {
            g  += Wbil[t*256 + c] * bp[c];
            g2 += Wbil[c*256 + t] * bp[c];
        }
        h[t] = g + g2;
        __shared__ float red[256];
        red[t] = bp[t] * g;
        __syncthreads();
        for (int s2 = 128; s2 > 0; s2 >>= 1) {
            if (t < s2) red[t] += red[t + s2];
            __syncthreads();
        }
        if (t == 0) c0[0] = red[0];
    }
}

// ============ K0b: Q = Wp^T @ T ; c1 = Wp^T @ h ============
__global__ __launch_bounds__(256) void k0b(
    const float* __restrict__ Wp, const float* __restrict__ T,
    const float* __restrict__ h,
    float* __restrict__ Q, float* __restrict__ c1)
{
    int t = threadIdx.x, bk = blockIdx.x;
    for (int m = 0; m < 4; ++m) {
        int d = bk*4 + m;
        float acc = 0.f;
        for (int a = 0; a < 256; ++a) acc += Wp[a*256 + d] * T[a*256 + t];
        Q[d*256 + t] = acc;
    }
    if (t < 4) {
        int d = bk*4 + t;
        float acc = 0.f;
        for (int a = 0; a < 256; ++a) acc += Wp[a*256 + d] * h[a];
        c1[d] = acc;
    }
}

// ============ K1: per-row s -> E=exp(s), f ============
// fused GEMM: u[r,e] = sum_d str[r,d] Q[d,e]; s_r = sum_e (u+c1)[e]*str[r,e] + c0 + bbil
__global__ __launch_bounds__(256) void k_rowstats(
    const float* __restrict__ input, const float* __restrict__ Q,
    const float* __restrict__ c1, const float* __restrict__ c0,
    const float* __restrict__ Wfi, const float* __restrict__ bbil,
    const float* __restrict__ bfi,
    float* __restrict__ Ev, float* __restrict__ fv)
{
    __shared__ __align__(16) float As[64][33];
    __shared__ __align__(16) float Ws[32][256];
    __shared__ float sred[64][17];
    __shared__ float fred[64][17];
    int t = threadIdx.x;
    int tx = t & 15, ty = t >> 4;
    long rowbase = (long)blockIdx.x * 64;
    const float* Ab = input + rowbase*DIM_ + SEM_;   // str part
    float acc[4][16];
#pragma unroll
    for (int m = 0; m < 4; ++m)
#pragma unroll
        for (int c = 0; c < 16; ++c) acc[m][c] = 0.f;

    for (int k0 = 0; k0 < 256; k0 += 32) {
#pragma unroll
        for (int j = 0; j < 2; ++j) {
            int v = t + 256*j;
            int r = v >> 3, kq = v & 7;
            float4 a4 = *(const float4*)(Ab + (long)r*DIM_ + k0 + kq*4);
            As[r][kq*4+0] = a4.x; As[r][kq*4+1] = a4.y;
            As[r][kq*4+2] = a4.z; As[r][kq*4+3] = a4.w;
        }
#pragma unroll
        for (int j = 0; j < 8; ++j) {
            int v = t + 256*j;
            int kk = v >> 6, c4 = v & 63;
            *(float4*)&Ws[kk][c4*4] = *(const float4*)(Q + (k0+kk)*256 + c4*4);
        }
        __syncthreads();
#pragma unroll
        for (int k = 0; k < 32; ++k) {
            float a0 = As[ty*4+0][k], a1 = As[ty*4+1][k];
            float a2 = As[ty*4+2][k], a3 = As[ty*4+3][k];
#pragma unroll
            for (int c = 0; c < 4; ++c) {
                float4 w = *(float4*)&Ws[k][tx*4 + 64*c];
                acc[0][c*4+0] += a0*w.x; acc[0][c*4+1] += a0*w.y;
                acc[0][c*4+2] += a0*w.z; acc[0][c*4+3] += a0*w.w;
                acc[1][c*4+0] += a1*w.x; acc[1][c*4+1] += a1*w.y;
                acc[1][c*4+2] += a1*w.z; acc[1][c*4+3] += a1*w.w;
                acc[2][c*4+0] += a2*w.x; acc[2][c*4+1] += a2*w.y;
                acc[2][c*4+2] += a2*w.z; acc[2][c*4+3] += a2*w.w;
                acc[3][c*4+0] += a3*w.x; acc[3][c*4+1] += a3*w.y;
                acc[3][c*4+2] += a3*w.z; acc[3][c*4+3] += a3*w.w;
            }
        }
        __syncthreads();
    }
    // epilogue: s and f partials
    float spart[4] = {0,0,0,0}, fpart[4] = {0,0,0,0};
#pragma unroll
    for (int c = 0; c < 4; ++c) {
        int e = tx*4 + 64*c;
        float4 c1v = *(const float4*)(c1 + e);
        float4 wfv = *(const float4*)(Wfi + e);
#pragma unroll
        for (int m = 0; m < 4; ++m) {
            int r = ty*4 + m;
            float4 sv = *(const float4*)(Ab + (long)r*DIM_ + e);
            spart[m] += (acc[m][c*4+0] + c1v.x)*sv.x + (acc[m][c*4+1] + c1v.y)*sv.y
                      + (acc[m][c*4+2] + c1v.z)*sv.z + (acc[m][c*4+3] + c1v.w)*sv.w;
            fpart[m] += wfv.x*sv.x + wfv.y*sv.y + wfv.z*sv.z + wfv.w*sv.w;
        }
    }
#pragma unroll
    for (int m = 0; m < 4; ++m) {
        sred[ty*4+m][tx] = spart[m];
        fred[ty*4+m][tx] = fpart[m];
    }
    __syncthreads();
    if (t < 64) {
        float ss = 0.f, ff = 0.f;
#pragma unroll
        for (int x = 0; x < 16; ++x) { ss += sred[t][x]; ff += fred[t][x]; }
        Ev[rowbase + t] = expf(ss + c0[0] + bbil[0]);
        fv[rowbase + t] = expf(ff + bfi[0]);
    }
}

// ============ K2a: partial sumvec (j>=1) and partial F per batch ============
__global__ __launch_bounds__(256) void k_batchsum(
    const float* __restrict__ input, const float* __restrict__ Ev,
    const float* __restrict__ fv,
    float* __restrict__ sump, float* __restrict__ Fpart)
{
    int b = blockIdx.x >> 2, part = blockIdx.x & 3;
    int d = threadIdx.x;
    int j0 = part*128;
    float acc = 0.f;
    for (int jj = (part == 0 ? 1 : 0); jj < 128; ++jj) {
        int j = j0 + jj;
        float Ej = Ev[b*512 + j];
        acc += Ej * input[((long)(b*512 + j))*DIM_ + d];   // sem part (d < 256)
    }
    sump[(b*4 + part)*256 + d] = acc;

    __shared__ float fr[128];
    if (d < 128) fr[d] = fv[b*512 + j0 + d];
    __syncthreads();
    for (int s2 = 64; s2 >= 1; s2 >>= 1) {
        if (d < s2) fr[d] += fr[d + s2];
        __syncthreads();
    }
    if (d == 0) Fpart[b*4 + part] = fr[0];
}

// ============ K2b: v2b, v0b, F ============
__global__ __launch_bounds__(256) void k_vcalc(
    const float* __restrict__ input, const float* __restrict__ Wfz,
    const float* __restrict__ Ev, const float* __restrict__ sump,
    const float* __restrict__ Fpart,
    float* __restrict__ v2b, float* __restrict__ v0b, float* __restrict__ Fws)
{
    int b = blockIdx.x, t = threadIdx.x;
    __shared__ float sv[256];
    __shared__ float s0[256];
    sv[t] = sump[(b*4+0)*256+t] + sump[(b*4+1)*256+t]
          + sump[(b*4+2)*256+t] + sump[(b*4+3)*256+t];
    s0[t] = input[((long)(b*512))*DIM_ + t];   // sem[b,0,t]
    __syncthreads();
    float E0 = Ev[b*512];
    const float* w2 = Wfz + t*512 + 256;
    float a2 = 0.f, a0 = 0.f;
    for (int dd = 0; dd < 256; ++dd) {
        float w = w2[dd];
        a2 += w * s0[dd];
        a0 += w * sv[dd];
    }
    v2b[b*256 + t] = E0 * a2;
    v0b[b*256 + t] = a0;
    if (t == 0) Fws[b] = Fpart[b*4] + Fpart[b*4+1] + Fpart[b*4+2] + Fpart[b*4+3];
}

// ============ K3: fused final GEMM + rank-2 epilogue + ReLU ============
__global__ __launch_bounds__(256) void k_final(
    const float* __restrict__ input, const float* __restrict__ Wt1,
    const float* __restrict__ v1, const float* __restrict__ v2b,
    const float* __restrict__ v0b, const float* __restrict__ Ev,
    const float* __restrict__ fv, const float* __restrict__ Fws,
    const float* __restrict__ bfz, float* __restrict__ out)
{
    __shared__ __align__(16) float As[64][33];
    __shared__ __align__(16) float Ws[32][256];
    __shared__ float cA[64], cB[64];
    int t = threadIdx.x, tx = t & 15, ty = t >> 4;
    long rowbase = (long)blockIdx.x * 64;
    int b = (int)(rowbase >> 9);
    const float* Ab = input + rowbase*DIM_;   // sem part
    if (t < 64) {
        int row = (int)rowbase + t;
        int i = row & 511;
        float invF = 1.0f / Fws[b];
        float fr = fv[row];
        cA[t] = fr * invF;                         // d0
        if (i == 0) cB[t] = -invF;                 // -dg0
        else cB[t] = (1.0f + (fv[b*512] - fr)*invF) / (512.0f * Ev[row]);  // dg_i
    }
    float acc[4][16];
#pragma unroll
    for (int m = 0; m < 4; ++m)
#pragma unroll
        for (int c = 0; c < 16; ++c) acc[m][c] = 0.f;

    for (int k0 = 0; k0 < 256; k0 += 32) {
#pragma unroll
        for (int j = 0; j < 2; ++j) {
            int v = t + 256*j;
            int r = v >> 3, kq = v & 7;
            float4 a4 = *(const float4*)(Ab + (long)r*DIM_ + k0 + kq*4);
            As[r][kq*4+0] = a4.x; As[r][kq*4+1] = a4.y;
            As[r][kq*4+2] = a4.z; As[r][kq*4+3] = a4.w;
        }
#pragma unroll
        for (int j = 0; j < 8; ++j) {
            int v = t + 256*j;
            int kk = v >> 6, c4 = v & 63;
            *(float4*)&Ws[kk][c4*4] = *(const float4*)(Wt1 + (k0+kk)*256 + c4*4);
        }
        __syncthreads();
#pragma unroll
        for (int k = 0; k < 32; ++k) {
            float a0 = As[ty*4+0][k], a1 = As[ty*4+1][k];
            float a2 = As[ty*4+2][k], a3 = As[ty*4+3][k];
#pragma unroll
            for (int c = 0; c < 4; ++c) {
                float4 w = *(float4*)&Ws[k][tx*4 + 64*c];
                acc[0][c*4+0] += a0*w.x; acc[0][c*4+1] += a0*w.y;
                acc[0][c*4+2] += a0*w.z; acc[0][c*4+3] += a0*w.w;
                acc[1][c*4+0] += a1*w.x; acc[1][c*4+1] += a1*w.y;
                acc[1][c*4+2] += a1*w.z; acc[1][c*4+3] += a1*w.w;
                acc[2][c*4+0] += a2*w.x; acc[2][c*4+1] += a2*w.y;
                acc[2][c*4+2] += a2*w.z; acc[2][c*4+3] += a2*w.w;
                acc[3][c*4+0] += a3*w.x; acc[3][c*4+1] += a3*w.y;
                acc[3][c*4+2] += a3*w.z; acc[3][c*4+3] += a3*w.w;
            }
        }
        __syncthreads();
    }
    // epilogue
#pragma unroll
    for (int c = 0; c < 4; ++c) {
        int o = tx*4 + 64*c;
        float4 vv1 = *(const float4*)(v1 + o);
        float4 vv2 = *(const float4*)(v2b + b*256 + o);
        float4 vv0 = *(const float4*)(v0b + b*256 + o);
        float4 bz  = *(const float4*)(bfz + o);
#pragma unroll
        for (int m = 0; m < 4; ++m) {
            int r = ty*4 + m;
            int i = ((int)rowbase + r) & 511;
            float ca = cA[r], cb = cB[r];
            float4 sel = (i == 0) ? vv0 : vv2;
            float4 res;
            res.x = fmaxf(acc[m][c*4+0] + ca*vv1.x + cb*sel.x + bz.x, 0.f);
            res.y = fmaxf(acc[m][c*4+1] + ca*vv1.y + cb*sel.y + bz.y, 0.f);
            res.z = fmaxf(acc[m][c*4+2] + ca*vv1.z + cb*sel.z + bz.z, 0.f);
            res.w = fmaxf(acc[m][c*4+3] + ca*vv1.w + cb*sel.w + bz.w, 0.f);
            *(float4*)(out + ((long)(rowbase + r))*256 + o) = res;
        }
    }
}

extern "C" void kernel_launch(void* const* d_in, const int* in_sizes, int n_in,
                              void* d_out, int out_size, void* d_ws, size_t ws_size,
                              hipStream_t stream) {
    const float* input   = (const float*)d_in[0];
    const float* Wp      = (const float*)d_in[1];
    const float* bp      = (const float*)d_in[2];
    const float* Wbil    = (const float*)d_in[3];
    const float* bbil    = (const float*)d_in[4];
    const float* Wfi     = (const float*)d_in[5];
    const float* bfi     = (const float*)d_in[6];
    const float* exparam = (const float*)d_in[7];
    const float* Wfz     = (const float*)d_in[8];
    const float* bfz     = (const float*)d_in[9];
    float* ws  = (float*)d_ws;
    float* out = (float*)d_out;

    float* Q     = ws + OFF_Q;
    float* T     = ws + OFF_T;
    float* Wt1   = ws + OFF_WT1;
    float* v1    = ws + OFF_V1;
    float* c1    = ws + OFF_C1;
    float* h     = ws + OFF_H;
    float* c0    = ws + OFF_C0;
    float* Ev    = ws + OFF_EV;
    float* fv    = ws + OFF_FV;
    float* sump  = ws + OFF_SUMP;
    float* Fpart = ws + OFF_FPART;
    float* Fws   = ws + OFF_FWS;
    float* v2b   = ws + OFF_V2B;
    float* v0b   = ws + OFF_V0B;

    k0a<<<64, 256, 0, stream>>>(Wp, bp, Wbil, Wfz, exparam, T, Wt1, v1, h, c0);
    k0b<<<64, 256, 0, stream>>>(Wp, T, h, Q, c1);
    k_rowstats<<<ROWS_/64, 256, 0, stream>>>(input, Q, c1, c0, Wfi, bbil, bfi, Ev, fv);
    k_batchsum<<<B_*4, 256, 0, stream>>>(input, Ev, fv, sump, Fpart);
    k_vcalc<<<B_, 256, 0, stream>>>(input, Wfz, Ev, sump, Fpart, v2b, v0b, Fws);
    k_final<<<ROWS_/64, 256, 0, stream>>>(input, Wt1, v1, v2b, v0b, Ev, fv, Fws, bfz, out);
}

// Round 2
// 100.172 us; speedup vs baseline: 2.3618x; 2.3618x over previous
//
#include <hip/hip_runtime.h>
#include <math.h>

#define B_    64
#define N_    512
#define SEM_  256
#define STR_  256
#define DIM_  512              // SEM+STR
#define ROWS_ (B_*N_)          // 32768

// ---- workspace layout (float offsets) ----
#define OFF_T      0           // 256x256 f32 (Wbil@Wp temp)
#define OFF_QT16   65536       // 256x256 bf16 (ushort), Qt[e][d] = Q[d][e]
#define OFF_W116   98304       // 256x256 bf16 (ushort), W116[o][d] = Wfz[o][d]
#define OFF_V1     131072      // 256  Wfz2 @ exparam
#define OFF_C1     131328      // 256  Wp^T (Wbil+Wbil^T) bp
#define OFF_H      131584      // 256
#define OFF_C0     131840      // 1 (padded)
#define OFF_EV     131904      // 32768
#define OFF_FV     164672      // 32768
#define OFF_SUMP   197440      // 64*8*256
#define OFF_FPART  328512      // 512
#define OFF_FWS    329024      // 64
#define OFF_V2B    329088      // 64*256
#define OFF_V0B    345472      // 64*256   (end: 361856 floats = 1.45 MB)

typedef __bf16 bf16x8 __attribute__((ext_vector_type(8)));
typedef float  f32x4  __attribute__((ext_vector_type(4)));

__device__ __forceinline__ ushort f2b(float x) {
    unsigned u = __builtin_bit_cast(unsigned, x);
    u += 0x7FFFu + ((u >> 16) & 1u);      // round-to-nearest-even
    return (ushort)(u >> 16);
}
__device__ __forceinline__ float b2f(ushort h) {
    unsigned u = ((unsigned)h) << 16;
    return __builtin_bit_cast(float, u);
}

// ============ K0a: T = Wbil@Wp ; W116 = bf16(Wfz[:, :256]) ; v1, h, c0 ============
__global__ __launch_bounds__(256) void k0a(
    const float* __restrict__ Wp, const float* __restrict__ bp,
    const float* __restrict__ Wbil, const float* __restrict__ Wfz,
    const float* __restrict__ exparam,
    float* __restrict__ T, ushort* __restrict__ W116,
    float* __restrict__ v1, float* __restrict__ h, float* __restrict__ c0)
{
    int t = threadIdx.x, a = blockIdx.x;
    float acc = 0.f;
    const float* wb = Wbil + a*256;
    for (int c = 0; c < 256; ++c) acc += wb[c] * Wp[c*256 + t];
    T[a*256 + t] = acc;
    W116[a*256 + t] = f2b(Wfz[a*512 + t]);
    if (a == 0) {
        float s = 0.f;
        const float* w2 = Wfz + t*512 + 256;
        for (int dd = 0; dd < 256; ++dd) s += w2[dd] * exparam[dd];
        v1[t] = s;
    }
    if (a == 1) {
        float g = 0.f, g2 = 0.f;
        for (int c = 0; c < 256; ++c) {
            g  += Wbil[t*256 + c] * bp[c];
            g2 += Wbil[c*256 + t] * bp[c];
        }
        h[t] = g + g2;
        __shared__ float red[256];
        red[t] = bp[t] * g;
        __syncthreads();
        for (int s2 = 128; s2 > 0; s2 >>= 1) {
            if (t < s2) red[t] += red[t + s2];
            __syncthreads();
        }
        if (t == 0) c0[0] = red[0];
    }
}

// ============ K0b: Qt16[e][d] = bf16((Wp^T @ T)[d][e]) ; c1 = Wp^T @ h ============
__global__ __launch_bounds__(256) void k0b(
    const float* __restrict__ Wp, const float* __restrict__ T,
    const float* __restrict__ h,
    ushort* __restrict__ Qt16, float* __restrict__ c1)
{
    int t = threadIdx.x, d = blockIdx.x;
    float acc = 0.f;
    for (int a2 = 0; a2 < 256; ++a2) acc += Wp[a2*256 + d] * T[a2*256 + t];
    Qt16[t*256 + d] = f2b(acc);          // transposed store (e-major)
    __shared__ float red[256];
    red[t] = Wp[t*256 + d] * h[t];
    __syncthreads();
    for (int s2 = 128; s2 > 0; s2 >>= 1) {
        if (t < s2) red[t] += red[t + s2];
        __syncthreads();
    }
    if (t == 0) c1[d] = red[0];
}

// ============ K1: MFMA GEMM u = str@Q -> s, f -> Ev, fv ============
__global__ __launch_bounds__(256) void k_rowstats(
    const float* __restrict__ input, const ushort* __restrict__ Qt16,
    const float* __restrict__ c1, const float* __restrict__ c0,
    const float* __restrict__ Wfi, const float* __restrict__ bbil,
    const float* __restrict__ bfi,
    float* __restrict__ Ev, float* __restrict__ fv)
{
    __shared__ __align__(16) ushort Ash[64][264];   // str tile, bf16, stride 528B
    __shared__ __align__(16) ushort Bs[256][40];    // Q^T K-slice, stride 80B
    __shared__ float sred[64][4];
    __shared__ float fred[64][4];
    int t = threadIdx.x;
    int lane = t & 63, w = t >> 6;
    int g = lane >> 4, li = lane & 15;
    long rowbase = (long)blockIdx.x * 64;
    const float* Ab = input + rowbase*DIM_ + SEM_;   // str half

    // stage A tile once: 64 rows x 256 k, fp32 -> bf16
#pragma unroll
    for (int q = 0; q < 16; ++q) {
        int v = t + 256*q;
        int r = v >> 6, c4 = v & 63;
        float4 a4 = *(const float4*)(Ab + (long)r*DIM_ + c4*4);
        ushort4 b4 = make_ushort4(f2b(a4.x), f2b(a4.y), f2b(a4.z), f2b(a4.w));
        *(ushort4*)&Ash[r][c4*4] = b4;
    }

    f32x4 acc[4][4];
#pragma unroll
    for (int m = 0; m < 4; ++m)
#pragma unroll
        for (int n = 0; n < 4; ++n) acc[m][n] = (f32x4){0.f, 0.f, 0.f, 0.f};

    for (int k0 = 0; k0 < 256; k0 += 32) {
        // stage B slice: Bs[e][kk] = Qt16[e*256 + k0+kk]
#pragma unroll
        for (int q = 0; q < 4; ++q) {
            int v = t + 256*q;
            int n = v >> 2, c = v & 3;
            *(uint4*)&Bs[n][c*8] = *(const uint4*)&Qt16[n*256 + k0 + c*8];
        }
        __syncthreads();
        bf16x8 af[4], bfr[4];
#pragma unroll
        for (int m = 0; m < 4; ++m)
            af[m] = *(const bf16x8*)&Ash[m*16 + li][k0 + g*8];
#pragma unroll
        for (int n = 0; n < 4; ++n)
            bfr[n] = *(const bf16x8*)&Bs[w*64 + n*16 + li][g*8];
#pragma unroll
        for (int m = 0; m < 4; ++m)
#pragma unroll
            for (int n = 0; n < 4; ++n)
                acc[m][n] = __builtin_amdgcn_mfma_f32_16x16x32_bf16(af[m], bfr[n], acc[m][n], 0, 0, 0);
        __syncthreads();
    }

    // epilogue: s_r = sum_e (u+c1)*str ; f_r = sum_e Wfi*str
    float c1v[4], wfv[4];
#pragma unroll
    for (int n = 0; n < 4; ++n) {
        int col = w*64 + n*16 + li;
        c1v[n] = c1[col];
        wfv[n] = Wfi[col];
    }
#pragma unroll
    for (int m = 0; m < 4; ++m) {
#pragma unroll
        for (int reg = 0; reg < 4; ++reg) {
            int row = m*16 + g*4 + reg;
            float sp = 0.f, fp = 0.f;
#pragma unroll
            for (int n = 0; n < 4; ++n) {
                int col = w*64 + n*16 + li;
                float sv = b2f(Ash[row][col]);
                sp += (acc[m][n][reg] + c1v[n]) * sv;
                fp += wfv[n] * sv;
            }
#pragma unroll
            for (int off = 1; off < 16; off <<= 1) {
                sp += __shfl_xor(sp, off);
                fp += __shfl_xor(fp, off);
            }
            if (li == 0) { sred[row][w] = sp; fred[row][w] = fp; }
        }
    }
    __syncthreads();
    if (t < 64) {
        float ss = sred[t][0] + sred[t][1] + sred[t][2] + sred[t][3];
        float ff = fred[t][0] + fred[t][1] + fred[t][2] + fred[t][3];
        Ev[rowbase + t] = expf(ss + c0[0] + bbil[0]);
        fv[rowbase + t] = expf(ff + bfi[0]);
    }
}

// ============ K2a: partial sumvec (j>=1) and partial F per batch ============
__global__ __launch_bounds__(256) void k_batchsum(
    const float* __restrict__ input, const float* __restrict__ Ev,
    const float* __restrict__ fv,
    float* __restrict__ sump, float* __restrict__ Fpart)
{
    int bk = blockIdx.x;
    int b = bk >> 3, part = bk & 7;
    int d = threadIdx.x;
    int j0 = part * 64;
    const float* base = input + ((long)(b*512 + j0))*DIM_;
    const float* ev = Ev + b*512 + j0;
    float acc = 0.f;
    for (int jj = (part == 0 ? 1 : 0); jj < 64; ++jj)
        acc += ev[jj] * base[(long)jj*DIM_ + d];
    sump[bk*256 + d] = acc;

    __shared__ float fr[64];
    if (d < 64) fr[d] = fv[b*512 + j0 + d];
    __syncthreads();
    for (int s2 = 32; s2 >= 1; s2 >>= 1) {
        if (d < s2) fr[d] += fr[d + s2];
        __syncthreads();
    }
    if (d == 0) Fpart[bk] = fr[0];
}

// ============ K2b: v2b, v0b, F ============
__global__ __launch_bounds__(256) void k_vcalc(
    const float* __restrict__ input, const float* __restrict__ Wfz,
    const float* __restrict__ Ev, const float* __restrict__ sump,
    const float* __restrict__ Fpart,
    float* __restrict__ v2b, float* __restrict__ v0b, float* __restrict__ Fws)
{
    int b = blockIdx.x, t = threadIdx.x;
    __shared__ float sv[256], s0[256];
    float a = 0.f;
    for (int p = 0; p < 8; ++p) a += sump[(b*8 + p)*256 + t];
    sv[t] = a;
    s0[t] = input[((long)(b*512))*DIM_ + t];
    __syncthreads();
    float E0 = Ev[b*512];
    const float* w2 = Wfz + t*512 + 256;
    float a2 = 0.f, a0 = 0.f;
    for (int dd = 0; dd < 256; ++dd) {
        float w = w2[dd];
        a2 += w * s0[dd];
        a0 += w * sv[dd];
    }
    v2b[b*256 + t] = E0 * a2;
    v0b[b*256 + t] = a0;
    if (t == 0) {
        float F = 0.f;
        for (int p = 0; p < 8; ++p) F += Fpart[b*8 + p];
        Fws[b] = F;
    }
}

// ============ K3: MFMA GEMM sem@Wfz1^T + rank-2 epilogue + ReLU ============
__global__ __launch_bounds__(256) void k_final(
    const float* __restrict__ input, const ushort* __restrict__ W116,
    const float* __restrict__ v1, const float* __restrict__ v2b,
    const float* __restrict__ v0b, const float* __restrict__ Ev,
    const float* __restrict__ fv, const float* __restrict__ Fws,
    const float* __restrict__ bfz, float* __restrict__ out)
{
    __shared__ __align__(16) ushort Ash[64][264];   // sem tile bf16 (reused as Csh f32)
    __shared__ __align__(16) ushort Bs[256][40];
    __shared__ float cAs[64], cBs[64];
    int t = threadIdx.x;
    int lane = t & 63, w = t >> 6;
    int g = lane >> 4, li = lane & 15;
    long rowbase = (long)blockIdx.x * 64;
    int b = (int)(rowbase >> 9);
    int i0 = (int)(rowbase & 511);
    const float* Ab = input + rowbase*DIM_;          // sem half

    if (t < 64) {
        int row = (int)rowbase + t;
        float invF = 1.0f / Fws[b];
        float fr = fv[row];
        cAs[t] = fr * invF;                          // d0
        cBs[t] = ((i0 + t) == 0) ? -invF
               : (1.0f + (fv[b*512] - fr)*invF) / (512.0f * Ev[row]);
    }

    // stage A tile once
#pragma unroll
    for (int q = 0; q < 16; ++q) {
        int v = t + 256*q;
        int r = v >> 6, c4 = v & 63;
        float4 a4 = *(const float4*)(Ab + (long)r*DIM_ + c4*4);
        ushort4 b4 = make_ushort4(f2b(a4.x), f2b(a4.y), f2b(a4.z), f2b(a4.w));
        *(ushort4*)&Ash[r][c4*4] = b4;
    }

    f32x4 acc[4][4];
#pragma unroll
    for (int m = 0; m < 4; ++m)
#pragma unroll
        for (int n = 0; n < 4; ++n) acc[m][n] = (f32x4){0.f, 0.f, 0.f, 0.f};

    for (int k0 = 0; k0 < 256; k0 += 32) {
#pragma unroll
        for (int q = 0; q < 4; ++q) {
            int v = t + 256*q;
            int n = v >> 2, c = v & 3;
            *(uint4*)&Bs[n][c*8] = *(const uint4*)&W116[n*256 + k0 + c*8];
        }
        __syncthreads();
        bf16x8 af[4], bfr[4];
#pragma unroll
        for (int m = 0; m < 4; ++m)
            af[m] = *(const bf16x8*)&Ash[m*16 + li][k0 + g*8];
#pragma unroll
        for (int n = 0; n < 4; ++n)
            bfr[n] = *(const bf16x8*)&Bs[w*64 + n*16 + li][g*8];
#pragma unroll
        for (int m = 0; m < 4; ++m)
#pragma unroll
            for (int n = 0; n < 4; ++n)
                acc[m][n] = __builtin_amdgcn_mfma_f32_16x16x32_bf16(af[m], bfr[n], acc[m][n], 0, 0, 0);
        __syncthreads();
    }

    // epilogue vectors (per-lane, 4 col positions)
    float v1v[4], v2v[4], v0v[4], bzv[4];
#pragma unroll
    for (int n = 0; n < 4; ++n) {
        int col = w*64 + n*16 + li;
        v1v[n] = v1[col];
        v2v[n] = v2b[b*256 + col];
        v0v[n] = v0b[b*256 + col];
        bzv[n] = bfz[col];
    }

    // two-half LDS repack for coalesced float4 stores
    float* Csh = (float*)&Ash[0][0];                 // [32][264] f32
#pragma unroll
    for (int hh = 0; hh < 2; ++hh) {
#pragma unroll
        for (int mm = 0; mm < 2; ++mm) {
            int m = hh*2 + mm;
#pragma unroll
            for (int reg = 0; reg < 4; ++reg) {
                int row = m*16 + g*4 + reg;
                float ca = cAs[row], cb = cBs[row];
                int irow = i0 + row;
#pragma unroll
                for (int n = 0; n < 4; ++n) {
                    int col = w*64 + n*16 + li;
                    float sel = (irow == 0) ? v0v[n] : v2v[n];
                    float val = acc[m][n][reg] + ca*v1v[n] + cb*sel + bzv[n];
                    Csh[(row - hh*32)*264 + col] = fmaxf(val, 0.f);
                }
            }
        }
        __syncthreads();
#pragma unroll
        for (int q = 0; q < 8; ++q) {
            int v = t + 256*q;
            int r = v >> 6, c4 = v & 63;
            *(float4*)(out + (rowbase + hh*32 + r)*256 + c4*4) = *(const float4*)&Csh[r*264 + c4*4];
        }
        __syncthreads();
    }
}

extern "C" void kernel_launch(void* const* d_in, const int* in_sizes, int n_in,
                              void* d_out, int out_size, void* d_ws, size_t ws_size,
                              hipStream_t stream) {
    const float* input   = (const float*)d_in[0];
    const float* Wp      = (const float*)d_in[1];
    const float* bp      = (const float*)d_in[2];
    const float* Wbil    = (const float*)d_in[3];
    const float* bbil    = (const float*)d_in[4];
    const float* Wfi     = (const float*)d_in[5];
    const float* bfi     = (const float*)d_in[6];
    const float* exparam = (const float*)d_in[7];
    const float* Wfz     = (const float*)d_in[8];
    const float* bfz     = (const float*)d_in[9];
    float* ws  = (float*)d_ws;
    float* out = (float*)d_out;

    float*  T     = ws + OFF_T;
    ushort* Qt16  = (ushort*)(ws + OFF_QT16);
    ushort* W116  = (ushort*)(ws + OFF_W116);
    float*  v1    = ws + OFF_V1;
    float*  c1    = ws + OFF_C1;
    float*  h     = ws + OFF_H;
    float*  c0    = ws + OFF_C0;
    float*  Ev    = ws + OFF_EV;
    float*  fv    = ws + OFF_FV;
    float*  sump  = ws + OFF_SUMP;
    float*  Fpart = ws + OFF_FPART;
    float*  Fws   = ws + OFF_FWS;
    float*  v2b   = ws + OFF_V2B;
    float*  v0b   = ws + OFF_V0B;

    k0a<<<256, 256, 0, stream>>>(Wp, bp, Wbil, Wfz, exparam, T, W116, v1, h, c0);
    k0b<<<256, 256, 0, stream>>>(Wp, T, h, Qt16, c1);
    k_rowstats<<<ROWS_/64, 256, 0, stream>>>(input, Qt16, c1, c0, Wfi, bbil, bfi, Ev, fv);
    k_batchsum<<<B_*8, 256, 0, stream>>>(input, Ev, fv, sump, Fpart);
    k_vcalc<<<B_, 256, 0, stream>>>(input, Wfz, Ev, sump, Fpart, v2b, v0b, Fws);
    k_final<<<ROWS_/64, 256, 0, stream>>>(input, W116, v1, v2b, v0b, Ev, fv, Fws, bfz, out);
}

// Round 3
// 93.803 us; speedup vs baseline: 2.5222x; 1.0679x over previous
//
#include <hip/hip_runtime.h>
#include <math.h>

#define B_    64
#define N_    512
#define SEM_  256
#define STR_  256
#define DIM_  512              // SEM+STR
#define ROWS_ (B_*N_)          // 32768

// ---- workspace layout (float offsets) ----
#define OFF_T      0           // 256x256 f32 (Wbil@Wp temp)
#define OFF_QT16   65536       // 256x256 bf16, Qt[e][d] = Q[d][e]
#define OFF_W116   98304       // 256x256 bf16, W116[o][d] = Wfz[o][d]
#define OFF_W2T    131072      // 256x256 f32, W2t[d][o] = Wfz[o][256+d]
#define OFF_V1     196608      // 256  Wfz2 @ exparam
#define OFF_C1     196864      // 256  Wp^T (Wbil+Wbil^T) bp
#define OFF_H      197120      // 256
#define OFF_C0     197376      // 1 (padded)
#define OFF_EV     197440      // 32768
#define OFF_FV     230208      // 32768
#define OFF_SUMP   262976      // 512*256 per-block partial sums
#define OFF_V2B    394048      // 64*256
#define OFF_ROW0   410432      // 64*256 pre-ReLU row-0 GEMM results

typedef __bf16 bf16x8 __attribute__((ext_vector_type(8)));
typedef float  f32x4  __attribute__((ext_vector_type(4)));

__device__ __forceinline__ ushort f2b(float x) {
    return __builtin_bit_cast(ushort, (__bf16)x);   // native v_cvt (RTNE)
}
__device__ __forceinline__ float b2f(ushort h) {
    unsigned u = ((unsigned)h) << 16;
    return __builtin_bit_cast(float, u);
}

// ============ K0a: T = Wbil@Wp ; W116 ; W2t ; v1, h, c0 ============
__global__ __launch_bounds__(256) void k0a(
    const float* __restrict__ Wp, const float* __restrict__ bp,
    const float* __restrict__ Wbil, const float* __restrict__ Wfz,
    const float* __restrict__ exparam,
    float* __restrict__ T, ushort* __restrict__ W116, float* __restrict__ W2t,
    float* __restrict__ v1, float* __restrict__ h, float* __restrict__ c0)
{
    int t = threadIdx.x, a = blockIdx.x;
    float acc = 0.f;
    const float* wb = Wbil + a*256;
    for (int c = 0; c < 256; ++c) acc += wb[c] * Wp[c*256 + t];
    T[a*256 + t] = acc;
    W116[a*256 + t] = f2b(Wfz[a*512 + t]);
    W2t[t*256 + a] = Wfz[a*512 + 256 + t];          // transposed Wfz2
    if (a == 0) {
        float s = 0.f;
        const float* w2 = Wfz + t*512 + 256;
        for (int dd = 0; dd < 256; ++dd) s += w2[dd] * exparam[dd];
        v1[t] = s;
    }
    if (a == 1) {
        float g = 0.f, g2 = 0.f;
        for (int c = 0; c < 256; ++c) {
            g  += Wbil[t*256 + c] * bp[c];
            g2 += Wbil[c*256 + t] * bp[c];
        }
        h[t] = g + g2;
        __shared__ float red[256];
        red[t] = bp[t] * g;
        __syncthreads();
        for (int s2 = 128; s2 > 0; s2 >>= 1) {
            if (t < s2) red[t] += red[t + s2];
            __syncthreads();
        }
        if (t == 0) c0[0] = red[0];
    }
}

// ============ K0b: Qt16[e][d] = bf16((Wp^T @ T)[d][e]) ; c1 ============
__global__ __launch_bounds__(256) void k0b(
    const float* __restrict__ Wp, const float* __restrict__ T,
    const float* __restrict__ h,
    ushort* __restrict__ Qt16, float* __restrict__ c1)
{
    int t = threadIdx.x, d = blockIdx.x;
    float acc = 0.f;
    for (int a2 = 0; a2 < 256; ++a2) acc += Wp[a2*256 + d] * T[a2*256 + t];
    Qt16[t*256 + d] = f2b(acc);          // transposed store (e-major)
    __shared__ float red[256];
    red[t] = Wp[t*256 + d] * h[t];
    __syncthreads();
    for (int s2 = 128; s2 > 0; s2 >>= 1) {
        if (t < s2) red[t] += red[t + s2];
        __syncthreads();
    }
    if (t == 0) c1[d] = red[0];
}

// ============ K1: MFMA GEMM u = str@Q -> Ev, fv ; row0 blocks: v2b ============
__global__ __launch_bounds__(256) void k_rowstats(
    const float* __restrict__ input, const ushort* __restrict__ Qt16,
    const float* __restrict__ c1, const float* __restrict__ c0,
    const float* __restrict__ Wfi, const float* __restrict__ bbil,
    const float* __restrict__ bfi, const float* __restrict__ W2t,
    float* __restrict__ Ev, float* __restrict__ fv, float* __restrict__ v2b)
{
    __shared__ __align__(16) ushort Ash[64][264];   // str tile, bf16
    __shared__ __align__(16) ushort Bs[256][40];    // Q^T K-slice
    __shared__ float sred[64][4];
    __shared__ float fred[64][4];
    __shared__ float s0sh[256];
    __shared__ float shE0;
    int t = threadIdx.x;
    int lane = t & 63, w = t >> 6;
    int g = lane >> 4, li = lane & 15;
    long rowbase = (long)blockIdx.x * 64;
    int b = (int)(rowbase >> 9);
    int i0 = (int)(rowbase & 511);
    const float* Ab = input + rowbase*DIM_ + SEM_;   // str half

#pragma unroll
    for (int q = 0; q < 16; ++q) {
        int v = t + 256*q;
        int r = v >> 6, c4 = v & 63;
        float4 a4 = *(const float4*)(Ab + (long)r*DIM_ + c4*4);
        ushort4 b4 = make_ushort4(f2b(a4.x), f2b(a4.y), f2b(a4.z), f2b(a4.w));
        *(ushort4*)&Ash[r][c4*4] = b4;
    }

    f32x4 acc[4][4];
#pragma unroll
    for (int m = 0; m < 4; ++m)
#pragma unroll
        for (int n = 0; n < 4; ++n) acc[m][n] = (f32x4){0.f, 0.f, 0.f, 0.f};

    for (int k0 = 0; k0 < 256; k0 += 32) {
#pragma unroll
        for (int q = 0; q < 4; ++q) {
            int v = t + 256*q;
            int n = v >> 2, c = v & 3;
            *(uint4*)&Bs[n][c*8] = *(const uint4*)&Qt16[n*256 + k0 + c*8];
        }
        __syncthreads();
        bf16x8 af[4], bfr[4];
#pragma unroll
        for (int m = 0; m < 4; ++m)
            af[m] = *(const bf16x8*)&Ash[m*16 + li][k0 + g*8];
#pragma unroll
        for (int n = 0; n < 4; ++n)
            bfr[n] = *(const bf16x8*)&Bs[w*64 + n*16 + li][g*8];
#pragma unroll
        for (int m = 0; m < 4; ++m)
#pragma unroll
            for (int n = 0; n < 4; ++n)
                acc[m][n] = __builtin_amdgcn_mfma_f32_16x16x32_bf16(af[m], bfr[n], acc[m][n], 0, 0, 0);
        __syncthreads();
    }

    // epilogue: s_r = sum_e (u+c1)*str ; f_r = sum_e Wfi*str
    float c1v[4], wfv[4];
#pragma unroll
    for (int n = 0; n < 4; ++n) {
        int col = w*64 + n*16 + li;
        c1v[n] = c1[col];
        wfv[n] = Wfi[col];
    }
#pragma unroll
    for (int m = 0; m < 4; ++m) {
#pragma unroll
        for (int reg = 0; reg < 4; ++reg) {
            int row = m*16 + g*4 + reg;
            float sp = 0.f, fp = 0.f;
#pragma unroll
            for (int n = 0; n < 4; ++n) {
                int col = w*64 + n*16 + li;
                float sv = b2f(Ash[row][col]);
                sp += (acc[m][n][reg] + c1v[n]) * sv;
                fp += wfv[n] * sv;
            }
#pragma unroll
            for (int off = 1; off < 16; off <<= 1) {
                sp += __shfl_xor(sp, off);
                fp += __shfl_xor(fp, off);
            }
            if (li == 0) { sred[row][w] = sp; fred[row][w] = fp; }
        }
    }
    __syncthreads();
    if (t < 64) {
        float ss = sred[t][0] + sred[t][1] + sred[t][2] + sred[t][3];
        float ff = fred[t][0] + fred[t][1] + fred[t][2] + fred[t][3];
        float ev = expf(ss + c0[0] + bbil[0]);
        Ev[rowbase + t] = ev;
        fv[rowbase + t] = expf(ff + bfi[0]);
        if (t == 0) shE0 = ev;
    }

    // v2b for the block owning batch row 0
    if (i0 == 0) {
        if (t < 64)
            *(float4*)&s0sh[t*4] = *(const float4*)(input + (long)b*512*DIM_ + t*4);
        __syncthreads();
        float a2 = 0.f;
        for (int d = 0; d < 256; ++d) a2 += W2t[d*256 + t] * s0sh[d];
        v2b[b*256 + t] = shE0 * a2;
    }
}

// ============ K3: MFMA GEMM sem@Wfz1^T + epilogue + sump partials ============
__global__ __launch_bounds__(256) void k_final(
    const float* __restrict__ input, const ushort* __restrict__ W116,
    const float* __restrict__ v1, const float* __restrict__ v2b,
    const float* __restrict__ Ev, const float* __restrict__ fv,
    const float* __restrict__ bfz,
    float* __restrict__ sump, float* __restrict__ row0pre,
    float* __restrict__ out)
{
    __shared__ __align__(16) ushort Ash[64][264];   // sem tile bf16 (reused as Csh)
    __shared__ __align__(16) ushort Bs[256][40];
    __shared__ float cAs[64], cBs[64];
    __shared__ float EvL[64];
    __shared__ float redF[256];
    int t = threadIdx.x;
    int lane = t & 63, w = t >> 6;
    int g = lane >> 4, li = lane & 15;
    long rowbase = (long)blockIdx.x * 64;
    int b = (int)(rowbase >> 9);
    int i0 = (int)(rowbase & 511);
    const float* Ab = input + rowbase*DIM_;          // sem half

    // Fws = sum fv over batch (per-block recompute)
    redF[t] = fv[b*512 + t] + fv[b*512 + 256 + t];
    __syncthreads();
    for (int s2 = 128; s2 > 0; s2 >>= 1) {
        if (t < s2) redF[t] += redF[t + s2];
        __syncthreads();
    }
    float invF = 1.0f / redF[0];
    __syncthreads();

    if (t < 64) {
        int row = (int)rowbase + t;
        float fr = fv[row];
        float ev = Ev[row];
        EvL[t] = ev;
        cAs[t] = fr * invF;                          // d0
        cBs[t] = ((i0 + t) == 0) ? -invF
               : (1.0f + (fv[b*512] - fr)*invF) / (512.0f * ev);
    }

    // stage A tile (sem, bf16)
#pragma unroll
    for (int q = 0; q < 16; ++q) {
        int v = t + 256*q;
        int r = v >> 6, c4 = v & 63;
        float4 a4 = *(const float4*)(Ab + (long)r*DIM_ + c4*4);
        ushort4 b4 = make_ushort4(f2b(a4.x), f2b(a4.y), f2b(a4.z), f2b(a4.w));
        *(ushort4*)&Ash[r][c4*4] = b4;
    }

    f32x4 acc[4][4];
#pragma unroll
    for (int m = 0; m < 4; ++m)
#pragma unroll
        for (int n = 0; n < 4; ++n) acc[m][n] = (f32x4){0.f, 0.f, 0.f, 0.f};

    for (int k0 = 0; k0 < 256; k0 += 32) {
#pragma unroll
        for (int q = 0; q < 4; ++q) {
            int v = t + 256*q;
            int n = v >> 2, c = v & 3;
            *(uint4*)&Bs[n][c*8] = *(const uint4*)&W116[n*256 + k0 + c*8];
        }
        __syncthreads();
        bf16x8 af[4], bfr[4];
#pragma unroll
        for (int m = 0; m < 4; ++m)
            af[m] = *(const bf16x8*)&Ash[m*16 + li][k0 + g*8];
#pragma unroll
        for (int n = 0; n < 4; ++n)
            bfr[n] = *(const bf16x8*)&Bs[w*64 + n*16 + li][g*8];
#pragma unroll
        for (int m = 0; m < 4; ++m)
#pragma unroll
            for (int n = 0; n < 4; ++n)
                acc[m][n] = __builtin_amdgcn_mfma_f32_16x16x32_bf16(af[m], bfr[n], acc[m][n], 0, 0, 0);
        __syncthreads();
    }

    // per-block partial: sum_{j in block, j>=1} Ev_j * sem[j][d]   (d = t)
    {
        float sp = 0.f;
        int rstart = (i0 == 0) ? 1 : 0;
        for (int r = rstart; r < 64; ++r) sp += EvL[r] * b2f(Ash[r][t]);
        sump[(long)blockIdx.x*256 + t] = sp;
    }

    // epilogue vectors
    float v1v[4], v2v[4], bzv[4];
#pragma unroll
    for (int n = 0; n < 4; ++n) {
        int col = w*64 + n*16 + li;
        v1v[n] = v1[col];
        v2v[n] = v2b[b*256 + col];
        bzv[n] = bfz[col];
    }

    __syncthreads();   // done reading Ash as sem; about to reuse as Csh
    float* Csh = (float*)&Ash[0][0];                 // [32][264] f32
#pragma unroll
    for (int hh = 0; hh < 2; ++hh) {
#pragma unroll
        for (int mm = 0; mm < 2; ++mm) {
            int m = hh*2 + mm;
#pragma unroll
            for (int reg = 0; reg < 4; ++reg) {
                int row = m*16 + g*4 + reg;
                float ca = cAs[row], cb = cBs[row];
                int irow = i0 + row;
#pragma unroll
                for (int n = 0; n < 4; ++n) {
                    int col = w*64 + n*16 + li;
                    float sel = (irow == 0) ? 0.f : v2v[n];
                    float val = acc[m][n][reg] + ca*v1v[n] + cb*sel + bzv[n];
                    if (irow == 0) row0pre[b*256 + col] = val;   // pre-ReLU, no v0 term
                    Csh[(row - hh*32)*264 + col] = fmaxf(val, 0.f);
                }
            }
        }
        __syncthreads();
#pragma unroll
        for (int q = 0; q < 8; ++q) {
            int v = t + 256*q;
            int r = v >> 6, c4 = v & 63;
            *(float4*)(out + (rowbase + hh*32 + r)*256 + c4*4) = *(const float4*)&Csh[r*264 + c4*4];
        }
        __syncthreads();
    }
}

// ============ K4: fixup row i=0 of each batch ============
__global__ __launch_bounds__(256) void k_fix(
    const float* __restrict__ sump, const float* __restrict__ fv,
    const float* __restrict__ W2t, const float* __restrict__ row0pre,
    float* __restrict__ out)
{
    int b = blockIdx.x, t = threadIdx.x;
    __shared__ float svsh[256];
    __shared__ float redF[256];
    float a = 0.f;
#pragma unroll
    for (int p = 0; p < 8; ++p) a += sump[(long)(b*8 + p)*256 + t];
    svsh[t] = a;
    redF[t] = fv[b*512 + t] + fv[b*512 + 256 + t];
    __syncthreads();
    for (int s2 = 128; s2 > 0; s2 >>= 1) {
        if (t < s2) redF[t] += redF[t + s2];
        __syncthreads();
    }
    float invF = 1.0f / redF[0];
    float a0 = 0.f;
    for (int d = 0; d < 256; ++d) a0 += W2t[d*256 + t] * svsh[d];
    out[((long)b*512)*256 + t] = fmaxf(row0pre[b*256 + t] - invF*a0, 0.f);
}

extern "C" void kernel_launch(void* const* d_in, const int* in_sizes, int n_in,
                              void* d_out, int out_size, void* d_ws, size_t ws_size,
                              hipStream_t stream) {
    const float* input   = (const float*)d_in[0];
    const float* Wp      = (const float*)d_in[1];
    const float* bp      = (const float*)d_in[2];
    const float* Wbil    = (const float*)d_in[3];
    const float* bbil    = (const float*)d_in[4];
    const float* Wfi     = (const float*)d_in[5];
    const float* bfi     = (const float*)d_in[6];
    const float* exparam = (const float*)d_in[7];
    const float* Wfz     = (const float*)d_in[8];
    const float* bfz     = (const float*)d_in[9];
    float* ws  = (float*)d_ws;
    float* out = (float*)d_out;

    float*  T     = ws + OFF_T;
    ushort* Qt16  = (ushort*)(ws + OFF_QT16);
    ushort* W116  = (ushort*)(ws + OFF_W116);
    float*  W2t   = ws + OFF_W2T;
    float*  v1    = ws + OFF_V1;
    float*  c1    = ws + OFF_C1;
    float*  h     = ws + OFF_H;
    float*  c0    = ws + OFF_C0;
    float*  Ev    = ws + OFF_EV;
    float*  fv    = ws + OFF_FV;
    float*  sump  = ws + OFF_SUMP;
    float*  v2b   = ws + OFF_V2B;
    float*  row0p = ws + OFF_ROW0;

    k0a<<<256, 256, 0, stream>>>(Wp, bp, Wbil, Wfz, exparam, T, W116, W2t, v1, h, c0);
    k0b<<<256, 256, 0, stream>>>(Wp, T, h, Qt16, c1);
    k_rowstats<<<ROWS_/64, 256, 0, stream>>>(input, Qt16, c1, c0, Wfi, bbil, bfi, W2t, Ev, fv, v2b);
    k_final<<<ROWS_/64, 256, 0, stream>>>(input, W116, v1, v2b, Ev, fv, bfz, sump, row0p, out);
    k_fix<<<B_, 256, 0, stream>>>(sump, fv, W2t, row0p, out);
}

// Round 4
// 88.981 us; speedup vs baseline: 2.6589x; 1.0542x over previous
//
#include <hip/hip_runtime.h>
#include <math.h>

#define B_    64
#define N_    512
#define SEM_  256
#define STR_  256
#define DIM_  512              // SEM+STR
#define ROWS_ (B_*N_)          // 32768

// ---- workspace layout (float offsets) ----
#define OFF_T      0           // 256x256 f32 (Wbil@Wp temp)
#define OFF_QT16   65536       // 256x256 bf16, Qt[e][d] = Q[d][e]
#define OFF_W116   98304       // 256x256 bf16, W116[o][d] = Wfz[o][d]
#define OFF_W2T    131072      // 256x256 f32, W2t[d][o] = Wfz[o][256+d]
#define OFF_V1     196608      // 256  Wfz2 @ exparam
#define OFF_C1     196864      // 256  Wp^T (Wbil+Wbil^T) bp
#define OFF_H      197120      // 256
#define OFF_C0     197376      // 1 (padded)
#define OFF_EV     197440      // 32768
#define OFF_FV     230208      // 32768
#define OFF_SUMP   262976      // 512*256 per-block partial sums
#define OFF_V2B    394048      // 64*256
#define OFF_ROW0   410432      // 64*256 pre-ReLU row-0 GEMM results

typedef __bf16 bf16x8 __attribute__((ext_vector_type(8)));
typedef float  f32x4  __attribute__((ext_vector_type(4)));

__device__ __forceinline__ ushort f2b(float x) {
    return __builtin_bit_cast(ushort, (__bf16)x);   // native v_cvt (RTNE)
}
__device__ __forceinline__ float b2f(ushort h) {
    unsigned u = ((unsigned)h) << 16;
    return __builtin_bit_cast(float, u);
}
__device__ __forceinline__ float bflo(unsigned u) {
    return __builtin_bit_cast(float, u << 16);
}
__device__ __forceinline__ float bfhi(unsigned u) {
    return __builtin_bit_cast(float, u & 0xffff0000u);
}

// ============ K0a: T = Wbil@Wp ; W116 ; W2t ; v1, h, c0 ============
__global__ __launch_bounds__(256) void k0a(
    const float* __restrict__ Wp, const float* __restrict__ bp,
    const float* __restrict__ Wbil, const float* __restrict__ Wfz,
    const float* __restrict__ exparam,
    float* __restrict__ T, ushort* __restrict__ W116, float* __restrict__ W2t,
    float* __restrict__ v1, float* __restrict__ h, float* __restrict__ c0)
{
    int t = threadIdx.x, a = blockIdx.x;
    float acc = 0.f;
    const float* wb = Wbil + a*256;
    for (int c = 0; c < 256; ++c) acc += wb[c] * Wp[c*256 + t];
    T[a*256 + t] = acc;
    W116[a*256 + t] = f2b(Wfz[a*512 + t]);
    W2t[t*256 + a] = Wfz[a*512 + 256 + t];          // transposed Wfz2
    if (a == 0) {
        float s = 0.f;
        const float* w2 = Wfz + t*512 + 256;
        for (int dd = 0; dd < 256; ++dd) s += w2[dd] * exparam[dd];
        v1[t] = s;
    }
    if (a == 1) {
        float g = 0.f, g2 = 0.f;
        for (int c = 0; c < 256; ++c) {
            g  += Wbil[t*256 + c] * bp[c];
            g2 += Wbil[c*256 + t] * bp[c];
        }
        h[t] = g + g2;
        __shared__ float red[256];
        red[t] = bp[t] * g;
        __syncthreads();
        for (int s2 = 128; s2 > 0; s2 >>= 1) {
            if (t < s2) red[t] += red[t + s2];
            __syncthreads();
        }
        if (t == 0) c0[0] = red[0];
    }
}

// ============ K0b: Qt16[e][d] = bf16((Wp^T @ T)[d][e]) ; c1 ============
__global__ __launch_bounds__(256) void k0b(
    const float* __restrict__ Wp, const float* __restrict__ T,
    const float* __restrict__ h,
    ushort* __restrict__ Qt16, float* __restrict__ c1)
{
    int t = threadIdx.x, d = blockIdx.x;
    float acc = 0.f;
    for (int a2 = 0; a2 < 256; ++a2) acc += Wp[a2*256 + d] * T[a2*256 + t];
    Qt16[t*256 + d] = f2b(acc);          // transposed store (e-major)
    __shared__ float red[256];
    red[t] = Wp[t*256 + d] * h[t];
    __syncthreads();
    for (int s2 = 128; s2 > 0; s2 >>= 1) {
        if (t < s2) red[t] += red[t + s2];
        __syncthreads();
    }
    if (t == 0) c1[d] = red[0];
}

// ============ K1: MFMA GEMM u = str@Q -> Ev, fv via diag-MFMA ============
__global__ __launch_bounds__(256) void k_rowstats(
    const float* __restrict__ input, const ushort* __restrict__ Qt16,
    const float* __restrict__ c1, const float* __restrict__ c0,
    const float* __restrict__ Wfi, const float* __restrict__ bbil,
    const float* __restrict__ bfi, const float* __restrict__ W2t,
    float* __restrict__ Ev, float* __restrict__ fv, float* __restrict__ v2b)
{
    __shared__ __align__(16) char smem[69632];
    ushort* Ash   = (ushort*)smem;              // [64][256] bf16, XOR-swizzled
    ushort* Bsm   = (ushort*)(smem + 32768);    // [256][40] bf16
    ushort* Ush   = (ushort*)(smem + 32768);    // [64][256] bf16 swz (epilogue, overlaps Bsm)
    float*  sdiag = (float*)(smem + 65536);     // [64][4]
    float*  fdiag = (float*)(smem + 66560);     // [64][4]
    float*  s0sh  = (float*)(smem + 67584);     // [256]
    float*  shE0  = (float*)(smem + 68608);

    int t = threadIdx.x;
    int lane = t & 63, w = t >> 6;
    int g = lane >> 4, li = lane & 15;
    long rowbase = (long)blockIdx.x * 64;
    int b = (int)(rowbase >> 9);
    int i0 = (int)(rowbase & 511);
    const float* Ab = input + rowbase*DIM_ + SEM_;   // str half

    // stage A (str) tile: fp32 -> bf16, swizzled
#pragma unroll
    for (int q = 0; q < 16; ++q) {
        int v = t + 256*q;
        int r = v >> 6, c4 = v & 63;
        float4 a4 = *(const float4*)(Ab + (long)r*DIM_ + c4*4);
        ushort4 b4 = make_ushort4(f2b(a4.x), f2b(a4.y), f2b(a4.z), f2b(a4.w));
        *(ushort4*)&Ash[r*256 + ((c4*4) ^ ((r & 7) << 3))] = b4;
    }

    f32x4 acc[4][4];
#pragma unroll
    for (int m = 0; m < 4; ++m)
#pragma unroll
        for (int n = 0; n < 4; ++n) acc[m][n] = (f32x4){0.f, 0.f, 0.f, 0.f};

    for (int k0 = 0; k0 < 256; k0 += 32) {
#pragma unroll
        for (int q = 0; q < 4; ++q) {
            int v = t + 256*q;
            int n = v >> 2, c = v & 3;
            *(uint4*)&Bsm[n*40 + c*8] = *(const uint4*)&Qt16[n*256 + k0 + c*8];
        }
        __syncthreads();
        bf16x8 af[4], bfr[4];
        int xs = (li & 7) << 3;
#pragma unroll
        for (int m = 0; m < 4; ++m)
            af[m] = *(const bf16x8*)&Ash[(m*16 + li)*256 + ((k0 + g*8) ^ xs)];
#pragma unroll
        for (int n = 0; n < 4; ++n)
            bfr[n] = *(const bf16x8*)&Bsm[(w*64 + n*16 + li)*40 + g*8];
#pragma unroll
        for (int m = 0; m < 4; ++m)
#pragma unroll
            for (int n = 0; n < 4; ++n)
                acc[m][n] = __builtin_amdgcn_mfma_f32_16x16x32_bf16(af[m], bfr[n], acc[m][n], 0, 0, 0);
        __syncthreads();
    }

    // ---- U' = u + c1 -> Ush (bf16, swizzled); Bsm is dead now ----
    float c1v[4];
#pragma unroll
    for (int n = 0; n < 4; ++n) c1v[n] = c1[w*64 + n*16 + li];
#pragma unroll
    for (int m = 0; m < 4; ++m)
#pragma unroll
        for (int n = 0; n < 4; ++n)
#pragma unroll
            for (int reg = 0; reg < 4; ++reg) {
                int row = m*16 + g*4 + reg;
                int col = w*64 + n*16 + li;
                Ush[row*256 + (col ^ ((row & 7) << 3))] = f2b(acc[m][n][reg] + c1v[n]);
            }
    __syncthreads();

    // ---- diag MFMA: s = diag(U' @ Str^T), f = Wfi-broadcast variant ----
    f32x4 dacc[4], facc[4];
#pragma unroll
    for (int m = 0; m < 4; ++m) { dacc[m] = (f32x4){0.f,0.f,0.f,0.f}; facc[m] = (f32x4){0.f,0.f,0.f,0.f}; }
#pragma unroll
    for (int kk = 0; kk < 2; ++kk) {
        int kb = (w*2 + kk)*32 + g*8;
        float4 wf0 = *(const float4*)(Wfi + kb);
        float4 wf1 = *(const float4*)(Wfi + kb + 4);
        bf16x8 afw = (bf16x8){(__bf16)wf0.x, (__bf16)wf0.y, (__bf16)wf0.z, (__bf16)wf0.w,
                              (__bf16)wf1.x, (__bf16)wf1.y, (__bf16)wf1.z, (__bf16)wf1.w};
        int xs = (li & 7) << 3;
#pragma unroll
        for (int m = 0; m < 4; ++m) {
            int ridx = (m*16 + li)*256 + (kb ^ xs);
            bf16x8 afu = *(const bf16x8*)&Ush[ridx];
            bf16x8 bfs = *(const bf16x8*)&Ash[ridx];
            dacc[m] = __builtin_amdgcn_mfma_f32_16x16x32_bf16(afu, bfs, dacc[m], 0, 0, 0);
            facc[m] = __builtin_amdgcn_mfma_f32_16x16x32_bf16(afw, bfs, facc[m], 0, 0, 0);
        }
    }
    // extract diagonal: lane owns D[row=g*4+reg][col=li]; diag when li == g*4+reg
    if (g == (li >> 2)) {
        int dr = li & 3;
#pragma unroll
        for (int m = 0; m < 4; ++m) {
            float dv = dr == 0 ? dacc[m][0] : dr == 1 ? dacc[m][1] : dr == 2 ? dacc[m][2] : dacc[m][3];
            sdiag[(m*16 + li)*4 + w] = dv;
        }
    }
    if (g == 0) {
#pragma unroll
        for (int m = 0; m < 4; ++m) fdiag[(m*16 + li)*4 + w] = facc[m][0];
    }
    __syncthreads();
    if (t < 64) {
        float ss = sdiag[t*4] + sdiag[t*4+1] + sdiag[t*4+2] + sdiag[t*4+3];
        float ff = fdiag[t*4] + fdiag[t*4+1] + fdiag[t*4+2] + fdiag[t*4+3];
        float ev = expf(ss + c0[0] + bbil[0]);
        Ev[rowbase + t] = ev;
        fv[rowbase + t] = expf(ff + bfi[0]);
        if (t == 0) shE0[0] = ev;
    }

    // v2b for the block owning batch row 0
    if (i0 == 0) {
        if (t < 64)
            *(float4*)&s0sh[t*4] = *(const float4*)(input + (long)b*512*DIM_ + t*4);
        __syncthreads();
        float a2 = 0.f;
        for (int d = 0; d < 256; ++d) a2 += W2t[d*256 + t] * s0sh[d];
        v2b[b*256 + t] = shE0[0] * a2;
    }
}

// ============ K3: MFMA GEMM sem@Wfz1^T + epilogue + sump partials ============
__global__ __launch_bounds__(256) void k_final(
    const float* __restrict__ input, const ushort* __restrict__ W116,
    const float* __restrict__ v1, const float* __restrict__ v2b,
    const float* __restrict__ Ev, const float* __restrict__ fv,
    const float* __restrict__ bfz,
    float* __restrict__ sump, float* __restrict__ row0pre,
    float* __restrict__ out)
{
    __shared__ __align__(16) char smem[62976];
    ushort* Ash    = (ushort*)smem;             // [64][256] bf16 swz
    ushort* Bsm    = (ushort*)(smem + 32768);   // [256][40]
    float*  Csh    = (float*)smem;              // [32][264] f32 (epilogue, overlaps Ash)
    float*  sumred = (float*)(smem + 53248);    // [8][256]
    float*  cAs    = (float*)(smem + 61440);    // 64
    float*  cBs    = (float*)(smem + 61696);    // 64
    float*  EvL    = (float*)(smem + 61952);    // 64
    float*  wred   = (float*)(smem + 62208);    // 4

    int t = threadIdx.x;
    int lane = t & 63, w = t >> 6;
    int g = lane >> 4, li = lane & 15;
    long rowbase = (long)blockIdx.x * 64;
    int b = (int)(rowbase >> 9);
    int i0 = (int)(rowbase & 511);
    const float* Ab = input + rowbase*DIM_;          // sem half

    // Fws = sum fv over batch via wave-shuffle reduce
    float fsum = fv[b*512 + t] + fv[b*512 + 256 + t];
#pragma unroll
    for (int off = 32; off >= 1; off >>= 1) fsum += __shfl_down(fsum, off);
    if (lane == 0) wred[w] = fsum;
    __syncthreads();
    float invF = 1.0f / (wred[0] + wred[1] + wred[2] + wred[3]);

    if (t < 64) {
        int row = (int)rowbase + t;
        float fr = fv[row];
        float ev = Ev[row];
        EvL[t] = (i0 == 0 && t == 0) ? 0.f : ev;     // exclude j=0 from sump
        cAs[t] = fr * invF;                          // d0
        cBs[t] = ((i0 + t) == 0) ? -invF
               : (1.0f + (fv[b*512] - fr)*invF) / (512.0f * ev);
    }

    // stage A (sem) tile, swizzled
#pragma unroll
    for (int q = 0; q < 16; ++q) {
        int v = t + 256*q;
        int r = v >> 6, c4 = v & 63;
        float4 a4 = *(const float4*)(Ab + (long)r*DIM_ + c4*4);
        ushort4 b4 = make_ushort4(f2b(a4.x), f2b(a4.y), f2b(a4.z), f2b(a4.w));
        *(ushort4*)&Ash[r*256 + ((c4*4) ^ ((r & 7) << 3))] = b4;
    }

    f32x4 acc[4][4];
#pragma unroll
    for (int m = 0; m < 4; ++m)
#pragma unroll
        for (int n = 0; n < 4; ++n) acc[m][n] = (f32x4){0.f, 0.f, 0.f, 0.f};

    for (int k0 = 0; k0 < 256; k0 += 32) {
#pragma unroll
        for (int q = 0; q < 4; ++q) {
            int v = t + 256*q;
            int n = v >> 2, c = v & 3;
            *(uint4*)&Bsm[n*40 + c*8] = *(const uint4*)&W116[n*256 + k0 + c*8];
        }
        __syncthreads();
        bf16x8 af[4], bfr[4];
        int xs = (li & 7) << 3;
#pragma unroll
        for (int m = 0; m < 4; ++m)
            af[m] = *(const bf16x8*)&Ash[(m*16 + li)*256 + ((k0 + g*8) ^ xs)];
#pragma unroll
        for (int n = 0; n < 4; ++n)
            bfr[n] = *(const bf16x8*)&Bsm[(w*64 + n*16 + li)*40 + g*8];
#pragma unroll
        for (int m = 0; m < 4; ++m)
#pragma unroll
            for (int n = 0; n < 4; ++n)
                acc[m][n] = __builtin_amdgcn_mfma_f32_16x16x32_bf16(af[m], bfr[n], acc[m][n], 0, 0, 0);
        __syncthreads();
    }

    // ---- sump partial: sum_{j in block, j!=0} Ev_j * sem[j][d], vectorized ----
    {
        int qq = t >> 5, c8 = t & 31;
        float p[8];
#pragma unroll
        for (int i = 0; i < 8; ++i) p[i] = 0.f;
#pragma unroll
        for (int rr = 0; rr < 8; ++rr) {
            int r = qq*8 + rr;
            float ev = EvL[r];
            uint4 uv = *(const uint4*)&Ash[r*256 + ((c8*8) ^ (rr << 3))];
            p[0] += ev * bflo(uv.x); p[1] += ev * bfhi(uv.x);
            p[2] += ev * bflo(uv.y); p[3] += ev * bfhi(uv.y);
            p[4] += ev * bflo(uv.z); p[5] += ev * bfhi(uv.z);
            p[6] += ev * bflo(uv.w); p[7] += ev * bfhi(uv.w);
        }
        *(float4*)&sumred[qq*256 + c8*8]     = (float4){p[0], p[1], p[2], p[3]};
        *(float4*)&sumred[qq*256 + c8*8 + 4] = (float4){p[4], p[5], p[6], p[7]};
    }
    __syncthreads();
    {
        float sp = 0.f;
#pragma unroll
        for (int qq = 0; qq < 8; ++qq) sp += sumred[qq*256 + t];
        sump[(long)blockIdx.x*256 + t] = sp;
    }

    // epilogue vectors
    float v1v[4], v2v[4], bzv[4];
#pragma unroll
    for (int n = 0; n < 4; ++n) {
        int col = w*64 + n*16 + li;
        v1v[n] = v1[col];
        v2v[n] = v2b[b*256 + col];
        bzv[n] = bfz[col];
    }

    // two-half LDS repack (Csh overlaps Ash; all Ash reads completed above)
#pragma unroll
    for (int hh = 0; hh < 2; ++hh) {
        __syncthreads();
#pragma unroll
        for (int mm = 0; mm < 2; ++mm) {
            int m = hh*2 + mm;
#pragma unroll
            for (int reg = 0; reg < 4; ++reg) {
                int row = m*16 + g*4 + reg;
                float ca = cAs[row], cb = cBs[row];
                int irow = i0 + row;
#pragma unroll
                for (int n = 0; n < 4; ++n) {
                    int col = w*64 + n*16 + li;
                    float sel = (irow == 0) ? 0.f : v2v[n];
                    float val = acc[m][n][reg] + ca*v1v[n] + cb*sel + bzv[n];
                    if (irow == 0) row0pre[b*256 + col] = val;   // pre-ReLU, no v0 term
                    Csh[(row - hh*32)*264 + col] = fmaxf(val, 0.f);
                }
            }
        }
        __syncthreads();
#pragma unroll
        for (int q = 0; q < 8; ++q) {
            int v = t + 256*q;
            int r = v >> 6, c4 = v & 63;
            *(float4*)(out + (rowbase + hh*32 + r)*256 + c4*4) = *(const float4*)&Csh[r*264 + c4*4];
        }
    }
}

// ============ K4: fixup row i=0 of each batch ============
__global__ __launch_bounds__(256) void k_fix(
    const float* __restrict__ sump, const float* __restrict__ fv,
    const float* __restrict__ W2t, const float* __restrict__ row0pre,
    float* __restrict__ out)
{
    int b = blockIdx.x, t = threadIdx.x;
    __shared__ float svsh[256];
    __shared__ float redF[256];
    float a = 0.f;
#pragma unroll
    for (int p = 0; p < 8; ++p) a += sump[(long)(b*8 + p)*256 + t];
    svsh[t] = a;
    redF[t] = fv[b*512 + t] + fv[b*512 + 256 + t];
    __syncthreads();
    for (int s2 = 128; s2 > 0; s2 >>= 1) {
        if (t < s2) redF[t] += redF[t + s2];
        __syncthreads();
    }
    float invF = 1.0f / redF[0];
    float a0 = 0.f;
    for (int d = 0; d < 256; ++d) a0 += W2t[d*256 + t] * svsh[d];
    out[((long)b*512)*256 + t] = fmaxf(row0pre[b*256 + t] - invF*a0, 0.f);
}

extern "C" void kernel_launch(void* const* d_in, const int* in_sizes, int n_in,
                              void* d_out, int out_size, void* d_ws, size_t ws_size,
                              hipStream_t stream) {
    const float* input   = (const float*)d_in[0];
    const float* Wp      = (const float*)d_in[1];
    const float* bp      = (const float*)d_in[2];
    const float* Wbil    = (const float*)d_in[3];
    const float* bbil    = (const float*)d_in[4];
    const float* Wfi     = (const float*)d_in[5];
    const float* bfi     = (const float*)d_in[6];
    const float* exparam = (const float*)d_in[7];
    const float* Wfz     = (const float*)d_in[8];
    const float* bfz     = (const float*)d_in[9];
    float* ws  = (float*)d_ws;
    float* out = (float*)d_out;

    float*  T     = ws + OFF_T;
    ushort* Qt16  = (ushort*)(ws + OFF_QT16);
    ushort* W116  = (ushort*)(ws + OFF_W116);
    float*  W2t   = ws + OFF_W2T;
    float*  v1    = ws + OFF_V1;
    float*  c1    = ws + OFF_C1;
    float*  h     = ws + OFF_H;
    float*  c0    = ws + OFF_C0;
    float*  Ev    = ws + OFF_EV;
    float*  fv    = ws + OFF_FV;
    float*  sump  = ws + OFF_SUMP;
    float*  v2b   = ws + OFF_V2B;
    float*  row0p = ws + OFF_ROW0;

    k0a<<<256, 256, 0, stream>>>(Wp, bp, Wbil, Wfz, exparam, T, W116, W2t, v1, h, c0);
    k0b<<<256, 256, 0, stream>>>(Wp, T, h, Qt16, c1);
    k_rowstats<<<ROWS_/64, 256, 0, stream>>>(input, Qt16, c1, c0, Wfi, bbil, bfi, W2t, Ev, fv, v2b);
    k_final<<<ROWS_/64, 256, 0, stream>>>(input, W116, v1, v2b, Ev, fv, bfz, sump, row0p, out);
    k_fix<<<B_, 256, 0, stream>>>(sump, fv, W2t, row0p, out);
}